// Round 7
// baseline (137.136 us; speedup 1.0000x reference)
//
#include <hip/hip_runtime.h>
#include <math.h>

typedef __bf16 bf16_t;
typedef bf16_t bf16x4 __attribute__((ext_vector_type(4)));
typedef bf16_t bf16x8 __attribute__((ext_vector_type(8)));
typedef float  f32x4  __attribute__((ext_vector_type(4)));

__device__ __forceinline__ float softplus_f(float x) {
    return (x > 20.f) ? x : log1pf(expf(x));
}

__device__ __forceinline__ float fast_rcp(float x) {
#if __has_builtin(__builtin_amdgcn_rcpf)
    return __builtin_amdgcn_rcpf(x);
#else
    return 1.0f / x;
#endif
}

// ============================================================================
// 4-wave GEMM core, on-the-fly B transpose (verified R3-R6 structure).
// MT = 16-row output groups. Compact LDS. Split-K 256/wave, 4 slices,
// register prefetch. out[i] raw sums, order (s0+s1)+(s2+s3).
// ============================================================================
template<bool AF32, int MT>
__device__ __forceinline__ void gemmT_core(const void* Aptr, const float* __restrict__ Wf,
                                           const int m_base, const int n_base,
                                           unsigned char* smem, const int t, f32x4* out) {
    constexpr int NA  = 2 * MT;
    constexpr int SWS = MT * 1152 + 4608;   // stage wave stride (bf16 elements)
    constexpr int CRS = MT * 1088;          // Cr wave stride (f32)
    __syncthreads();
    bf16_t* stage = (bf16_t*)smem;
    float*  Cr    = (float*)smem;
    const int lane = t & 63, w = t >> 6;
    bf16_t* As = stage + w * SWS;
    bf16_t* Bs = As + MT * 1152;
    const int r8 = lane >> 3, kb = lane & 7;
    const int fr = lane & 15, fq = lane >> 4, fk = fq * 8;
    const int bc = fr;
    const int br16 = fq * 16;

    const float*  Af = (const float*)Aptr  + (size_t)m_base * 1024 + w * 256 + kb * 8;
    const bf16_t* Ab = (const bf16_t*)Aptr + (size_t)m_base * 1024 + w * 256 + kb * 8;
    const float*  Bf = Wf + (size_t)(w * 256 + br16) * 1024 + n_base + bc * 4;

    f32x4 acc[MT][4] = {};
    bf16x8 pa[NA];
    f32x4 paf0[NA], paf1[NA];
    f32x4 pbf[16];

#pragma unroll
    for (int i = 0; i < NA; ++i) {
        if constexpr (AF32) {
            paf0[i] = *(const f32x4*)(Af + (size_t)(i * 8 + r8) * 1024);
            paf1[i] = *(const f32x4*)(Af + (size_t)(i * 8 + r8) * 1024 + 4);
        } else {
            pa[i] = *(const bf16x8*)(Ab + (size_t)(i * 8 + r8) * 1024);
        }
    }
#pragma unroll
    for (int i = 0; i < 16; ++i)
        pbf[i] = *(const f32x4*)(Bf + (size_t)i * 1024);

#pragma unroll
    for (int s = 0; s < 4; ++s) {
#pragma unroll
        for (int i = 0; i < NA; ++i) {
            bf16x8 av;
            if constexpr (AF32) {
#pragma unroll
                for (int e = 0; e < 4; ++e) {
                    av[e]     = (bf16_t)paf0[i][e];
                    av[e + 4] = (bf16_t)paf1[i][e];
                }
            } else {
                av = pa[i];
            }
            *(bf16x8*)&As[(i * 8 + r8) * 72 + kb * 8] = av;
        }
#pragma unroll
        for (int e = 0; e < 4; ++e) {
            bf16x8 lo, hi;
#pragma unroll
            for (int q = 0; q < 8; ++q) {
                lo[q] = (bf16_t)pbf[q][e];
                hi[q] = (bf16_t)pbf[q + 8][e];
            }
            *(bf16x8*)&Bs[(bc * 4 + e) * 72 + br16]     = lo;
            *(bf16x8*)&Bs[(bc * 4 + e) * 72 + br16 + 8] = hi;
        }
        if (s < 3) {
            const int off = (s + 1) * 64;
#pragma unroll
            for (int i = 0; i < NA; ++i) {
                if constexpr (AF32) {
                    paf0[i] = *(const f32x4*)(Af + (size_t)(i * 8 + r8) * 1024 + off);
                    paf1[i] = *(const f32x4*)(Af + (size_t)(i * 8 + r8) * 1024 + off + 4);
                } else {
                    pa[i] = *(const bf16x8*)(Ab + (size_t)(i * 8 + r8) * 1024 + off);
                }
            }
#pragma unroll
            for (int i = 0; i < 16; ++i)
                pbf[i] = *(const f32x4*)(Bf + (size_t)i * 1024 + (size_t)off * 1024);
        }
#pragma unroll
        for (int kh = 0; kh < 2; ++kh) {
            bf16x8 aF[MT], bF[4];
#pragma unroll
            for (int i = 0; i < MT; ++i)
                aF[i] = *(const bf16x8*)&As[(i * 16 + fr) * 72 + kh * 32 + fk];
#pragma unroll
            for (int j = 0; j < 4; ++j)
                bF[j] = *(const bf16x8*)&Bs[(j * 16 + fr) * 72 + kh * 32 + fk];
#pragma unroll
            for (int i = 0; i < MT; ++i)
#pragma unroll
                for (int j = 0; j < 4; ++j)
                    acc[i][j] = __builtin_amdgcn_mfma_f32_16x16x32_bf16(aF[i], bF[j], acc[i][j], 0, 0, 0);
        }
    }

    __syncthreads();
    {
        float* Crw = Cr + w * CRS;
        const int orow = fq * 4;
#pragma unroll
        for (int i = 0; i < MT; ++i)
#pragma unroll
            for (int j = 0; j < 4; ++j)
#pragma unroll
                for (int rr = 0; rr < 4; ++rr)
                    Crw[(i * 16 + orow + rr) * 68 + j * 16 + fr] = acc[i][j][rr];
    }
    __syncthreads();

    const int cc = (t & 15) * 4;
#pragma unroll
    for (int i = 0; i < MT; ++i) {
        const int row = (t >> 4) + i * 16;
        f32x4 s0 = *(const f32x4*)&Cr[0 * CRS + row * 68 + cc];
        f32x4 s1 = *(const f32x4*)&Cr[1 * CRS + row * 68 + cc];
        f32x4 s2 = *(const f32x4*)&Cr[2 * CRS + row * 68 + cc];
        f32x4 s3 = *(const f32x4*)&Cr[3 * CRS + row * 68 + cc];
        out[i] = (s0 + s1) + (s2 + s3);
    }
}

// ============================================================================
// Dual-GEMM K core (verified R5/R6): ONE 8-slice pipeline, waves 0-1 Km /
// 2-3 Kv, split-K 512 each. 32-row tile. Compact LDS.
// ============================================================================
__device__ __forceinline__ void gemmK_dual(const float* __restrict__ mu,
                                           const float* __restrict__ var,
                                           const float* __restrict__ Wkm,
                                           const float* __restrict__ Wkv,
                                           const int m_base, const int n_base,
                                           unsigned char* smem, const int t,
                                           f32x4 okm[2], f32x4 okv[2]) {
    constexpr int SWS = 2 * 1152 + 4608;
    constexpr int CRS = 2 * 1088;
    __syncthreads();
    bf16_t* stage = (bf16_t*)smem;
    float*  Cr    = (float*)smem;
    const int lane = t & 63, w = t >> 6;
    bf16_t* As = stage + w * SWS;
    bf16_t* Bs = As + 2 * 1152;
    const int r8 = lane >> 3, kb = lane & 7;
    const int fr = lane & 15, fq = lane >> 4, fk = fq * 8;
    const int bc = fr;
    const int br16 = fq * 16;

    const float* Asrc = (w < 2) ? mu : var;
    const float* Wsrc = (w < 2) ? Wkm : Wkv;
    const int kbase = (w & 1) * 512;

    const float* Af = Asrc + (size_t)m_base * 1024 + kbase + kb * 8;
    const float* Bf = Wsrc + (size_t)(kbase + br16) * 1024 + n_base + bc * 4;

    f32x4 acc[2][4] = {};
    f32x4 paf0[4], paf1[4];
    f32x4 pbf[16];

#pragma unroll
    for (int i = 0; i < 4; ++i) {
        paf0[i] = *(const f32x4*)(Af + (size_t)(i * 8 + r8) * 1024);
        paf1[i] = *(const f32x4*)(Af + (size_t)(i * 8 + r8) * 1024 + 4);
    }
#pragma unroll
    for (int i = 0; i < 16; ++i)
        pbf[i] = *(const f32x4*)(Bf + (size_t)i * 1024);

#pragma unroll
    for (int s = 0; s < 8; ++s) {
#pragma unroll
        for (int i = 0; i < 4; ++i) {
            bf16x8 av;
#pragma unroll
            for (int e = 0; e < 4; ++e) {
                av[e]     = (bf16_t)paf0[i][e];
                av[e + 4] = (bf16_t)paf1[i][e];
            }
            *(bf16x8*)&As[(i * 8 + r8) * 72 + kb * 8] = av;
        }
#pragma unroll
        for (int e = 0; e < 4; ++e) {
            bf16x8 lo, hi;
#pragma unroll
            for (int q = 0; q < 8; ++q) {
                lo[q] = (bf16_t)pbf[q][e];
                hi[q] = (bf16_t)pbf[q + 8][e];
            }
            *(bf16x8*)&Bs[(bc * 4 + e) * 72 + br16]     = lo;
            *(bf16x8*)&Bs[(bc * 4 + e) * 72 + br16 + 8] = hi;
        }
        if (s < 7) {
            const int off = (s + 1) * 64;
#pragma unroll
            for (int i = 0; i < 4; ++i) {
                paf0[i] = *(const f32x4*)(Af + (size_t)(i * 8 + r8) * 1024 + off);
                paf1[i] = *(const f32x4*)(Af + (size_t)(i * 8 + r8) * 1024 + off + 4);
            }
#pragma unroll
            for (int i = 0; i < 16; ++i)
                pbf[i] = *(const f32x4*)(Bf + (size_t)i * 1024 + (size_t)off * 1024);
        }
#pragma unroll
        for (int kh = 0; kh < 2; ++kh) {
            bf16x8 aF[2], bF[4];
#pragma unroll
            for (int i = 0; i < 2; ++i)
                aF[i] = *(const bf16x8*)&As[(i * 16 + fr) * 72 + kh * 32 + fk];
#pragma unroll
            for (int j = 0; j < 4; ++j)
                bF[j] = *(const bf16x8*)&Bs[(j * 16 + fr) * 72 + kh * 32 + fk];
#pragma unroll
            for (int i = 0; i < 2; ++i)
#pragma unroll
                for (int j = 0; j < 4; ++j)
                    acc[i][j] = __builtin_amdgcn_mfma_f32_16x16x32_bf16(aF[i], bF[j], acc[i][j], 0, 0, 0);
        }
    }

    __syncthreads();
    {
        float* Crw = Cr + w * CRS;
        const int orow = fq * 4;
#pragma unroll
        for (int i = 0; i < 2; ++i)
#pragma unroll
            for (int j = 0; j < 4; ++j)
#pragma unroll
                for (int rr = 0; rr < 4; ++rr)
                    Crw[(i * 16 + orow + rr) * 68 + j * 16 + fr] = acc[i][j][rr];
    }
    __syncthreads();

    const int cc = (t & 15) * 4;
#pragma unroll
    for (int i = 0; i < 2; ++i) {
        const int row = (t >> 4) + i * 16;
        okm[i] = *(const f32x4*)&Cr[0 * CRS + row * 68 + cc]
               + *(const f32x4*)&Cr[1 * CRS + row * 68 + cc];
        okv[i] = *(const f32x4*)&Cr[2 * CRS + row * 68 + cc]
               + *(const f32x4*)&Cr[3 * CRS + row * 68 + cc];
    }
}

// ============================================================================
// proj: 640 blocks, 32-row tiles, K blocks first (R6 verified layout).
// V outputs now stored TRANSPOSED: Vt[h][d=64][katt=256] bf16 (same rounding
// point -> bit-identical values; enables vectorized PV loads in attn).
// ============================================================================
#define PROJ_SMEM 55296

struct ProjArgs {
    const float* mu; const float* var;
    const float* W[6];
    const float* bias[6];
    float* Proj;                // slots: 0 Qm, 1 Qv (f32)
    bf16_t* Vtm; bf16_t* Vtv;   // [16 head][64 d][256 katt] bf16 (transposed)
    bf16_t* Gbf; float* cvec;
};

__global__ __launch_bounds__(256, 2) void proj_kernel(ProjArgs a) {
    __shared__ __align__(16) unsigned char smem[PROJ_SMEM];
    const int t = threadIdx.x;
    const int cc = (t & 15) * 4;
    const int L = blockIdx.x;

    if (L < 128) {
        // ---- type K ----
        const int x = L & 7, o = L >> 3;
        const int h  = (o >> 3) * 8 + x;
        const int mb = (o & 7) * 32;
        const int nb = h * 64;
        f32x4 okm[2], okv[2];
        gemmK_dual(a.mu, a.var, a.W[2], a.W[3], mb, nb, smem, t, okm, okv);
        const f32x4 bkm = *(const f32x4*)&a.bias[2][nb + cc];
        const f32x4 bkv = *(const f32x4*)&a.bias[3][nb + cc];
#pragma unroll
        for (int i = 0; i < 2; ++i) {
            const int row = (t >> 4) + i * 16;
            const int katt = mb + row;
            const f32x4 km  = okm[i] + bkm;
            const f32x4 kvr = okv[i] + bkv;
            bf16x4 o1, o2;
            float c = 0.f;
#pragma unroll
            for (int e = 0; e < 4; ++e) {
                const float kv = softplus_f(kvr[e]);
                const float r  = 0.5f * fast_rcp(kv);
                o1[e] = (bf16_t)r;
                o2[e] = (bf16_t)(-2.f * km[e] * r);
                c += km[e] * km[e] * r + 0.5f * __logf(kv);
            }
            bf16_t* grow = a.Gbf + ((size_t)(h * 256 + katt)) * 128;
            *(bf16x4*)&grow[cc]      = o1;
            *(bf16x4*)&grow[64 + cc] = o2;
#pragma unroll
            for (int off = 8; off > 0; off >>= 1)
                c += __shfl_xor(c, off, 16);
            if ((t & 15) == 0)
                a.cvec[h * 256 + katt] = c;
        }
    } else {
        // ---- type A (32-row tile) ----
        const int Lp = L - 128;
        const int x = Lp & 7, o = Lp >> 3;
        const int panel = (o >> 3) * 8 + x;     // 0..63
        const int mb = (o & 7) * 32;
        const int zp = panel >> 4;              // 0:Qm 1:Qv 2:Vm 3:Vv
        const int nb = (panel & 15) * 64;
        const int wi = (zp < 2) ? zp : (zp + 2);
        const int sp = (zp == 1) || (zp == 3);
        const void* A = sp ? (const void*)a.var : (const void*)a.mu;
        f32x4 ov[2];
        gemmT_core<true, 2>(A, a.W[wi], mb, nb, smem, t, ov);
        const f32x4 bv = *(const f32x4*)&a.bias[wi][nb + cc];
        if (zp < 2) {
            float* dst = a.Proj + (size_t)zp * 262144;
#pragma unroll
            for (int i = 0; i < 2; ++i) {
                const int row = (t >> 4) + i * 16;
                f32x4 v = ov[i] + bv;
                if (sp) {
                    v[0] = softplus_f(v[0]); v[1] = softplus_f(v[1]);
                    v[2] = softplus_f(v[2]); v[3] = softplus_f(v[3]);
                }
                *(f32x4*)&dst[(size_t)(mb + row) * 1024 + nb + cc] = v;
            }
        } else {
            // V transposed store: Vt[h][d][katt], d = cc+e, katt = mb+row
            bf16_t* dst = ((zp == 2) ? a.Vtm : a.Vtv) + (size_t)(nb >> 6) * 16384;
#pragma unroll
            for (int i = 0; i < 2; ++i) {
                const int row = (t >> 4) + i * 16;
                const int katt = mb + row;
                f32x4 v = ov[i] + bv;
                if (sp) {
                    v[0] = softplus_f(v[0]); v[1] = softplus_f(v[1]);
                    v[2] = softplus_f(v[2]); v[3] = softplus_f(v[3]);
                }
#pragma unroll
                for (int e = 0; e < 4; ++e)
                    dst[(size_t)(cc + e) * 256 + katt] = (bf16_t)v[e];
            }
        }
    }
}

// ============================================================================
// attention: V LDS staging REMOVED (V is L2-resident, 16 blocks share a head).
// PV B-fragment = one 16B global load from transposed Vt (j-contiguous).
// LDS: 58880 B (was 132608).
// ============================================================================
#define OFF_FS   0         // [16][132] f32 = 8448
#define OFF_SC   8448      // [16][260] f32 = 16640
#define OFF_PHI  25088     // [16][264] bf16 = 8448
#define OFF_PLO  33536
#define OFF_P2H  41984
#define OFF_P2L  50432
#define ATTN_SMEM 58880

__global__ __launch_bounds__(512) void attn_v8(const float* __restrict__ Qm,
                                               const float* __restrict__ Qv,
                                               const bf16_t* __restrict__ Gbf,
                                               const float* __restrict__ cvec,
                                               const bf16_t* __restrict__ Vtm,
                                               const bf16_t* __restrict__ Vtv,
                                               bf16_t* __restrict__ Omu,
                                               bf16_t* __restrict__ Ovar) {
    __shared__ __align__(16) unsigned char smem[ATTN_SMEM];
    float*  Fs  = (float*)(smem + OFF_FS);    // [16][132] f32
    float*  Sc  = (float*)(smem + OFF_SC);    // [16][260] f32
    bf16_t* Phi = (bf16_t*)(smem + OFF_PHI);  // [16][264] bf16
    bf16_t* Plo = (bf16_t*)(smem + OFF_PLO);
    bf16_t* P2h = (bf16_t*)(smem + OFF_P2H);
    bf16_t* P2l = (bf16_t*)(smem + OFF_P2L);

    const int L = blockIdx.x;
    const int h  = ((L >> 7) << 3) + (L & 7);
    const int qt = (L >> 3) & 15;

    const int t = threadIdx.x, w = t >> 6, lane = t & 63;
    const int fr = lane & 15, fq = lane >> 4;
    const int n0 = w * 32;

    const bf16_t* gB = Gbf + ((size_t)(h * 256 + n0 + fr)) * 128 + fq * 8;

    bf16x8 bcur[4];
#pragma unroll
    for (int ks = 0; ks < 4; ++ks) bcur[ks] = *(const bf16x8*)(gB + ks * 32);

    if (t < 256) {
        const int r = t >> 4, c = t & 15;
        f32x4 qm = *(const f32x4*)(Qm + (size_t)(qt * 16 + r) * 1024 + h * 64 + c * 4);
        f32x4 qv = *(const f32x4*)(Qv + (size_t)(qt * 16 + r) * 1024 + h * 64 + c * 4);
        *(f32x4*)&Fs[r * 132 + c * 4]      = qm * qm + qv;
        *(f32x4*)&Fs[r * 132 + 64 + c * 4] = qm;
    }
    __syncthreads();

    bf16x8 ahi[4], alo[4];
#pragma unroll
    for (int ks = 0; ks < 4; ++ks) {
        f32x4 f0 = *(const f32x4*)&Fs[fr * 132 + ks * 32 + fq * 8];
        f32x4 f1 = *(const f32x4*)&Fs[fr * 132 + ks * 32 + fq * 8 + 4];
#pragma unroll
        for (int e = 0; e < 4; ++e) {
            bf16_t hb = (bf16_t)f0[e];
            ahi[ks][e] = hb; alo[ks][e] = (bf16_t)(f0[e] - (float)hb);
            bf16_t hb2 = (bf16_t)f1[e];
            ahi[ks][e + 4] = hb2; alo[ks][e + 4] = (bf16_t)(f1[e] - (float)hb2);
        }
    }

    // scores: 2 n-tiles per wave (pure MFMA now; no V staging)
#pragma unroll
    for (int nt = 0; nt < 2; ++nt) {
        bf16x8 bnxt[4];
        if (nt < 1) {
#pragma unroll
            for (int ks = 0; ks < 4; ++ks)
                bnxt[ks] = *(const bf16x8*)(gB + 2048 + ks * 32);
        }

        f32x4 acc = {0.f, 0.f, 0.f, 0.f};
#pragma unroll
        for (int ks = 0; ks < 4; ++ks) {
            acc = __builtin_amdgcn_mfma_f32_16x16x32_bf16(ahi[ks], bcur[ks], acc, 0, 0, 0);
            acc = __builtin_amdgcn_mfma_f32_16x16x32_bf16(alo[ks], bcur[ks], acc, 0, 0, 0);
        }

        const float cv = cvec[h * 256 + n0 + nt * 16 + fr];
        f32x4 lg = (acc + cv) * (-0.125f);
#pragma unroll
        for (int reg = 0; reg < 4; ++reg)
            Sc[(fq * 4 + reg) * 260 + n0 + nt * 16 + fr] = lg[reg];

#pragma unroll
        for (int ks = 0; ks < 4; ++ks) bcur[ks] = bnxt[ks];
    }
    __syncthreads();

    const int fw = w * 2;
    f32x4 sr[2];
#pragma unroll
    for (int r = 0; r < 2; ++r)
        sr[r] = *(const f32x4*)&Sc[(fw + r) * 260 + lane * 4];
#pragma unroll
    for (int r = 0; r < 2; ++r) {
        f32x4 s = sr[r];
        float mloc = fmaxf(fmaxf(s[0], s[1]), fmaxf(s[2], s[3]));
#pragma unroll
        for (int off = 32; off > 0; off >>= 1)
            mloc = fmaxf(mloc, __shfl_xor(mloc, off, 64));
        s[0] = __expf(s[0] - mloc); s[1] = __expf(s[1] - mloc);
        s[2] = __expf(s[2] - mloc); s[3] = __expf(s[3] - mloc);
        float sl = (s[0] + s[1]) + (s[2] + s[3]);
#pragma unroll
        for (int off = 32; off > 0; off >>= 1)
            sl += __shfl_xor(sl, off, 64);
        sr[r] = s * fast_rcp(sl);
    }

#pragma unroll
    for (int r = 0; r < 2; ++r) {
        bf16x4 phi, plo, p2hi, p2lo;
#pragma unroll
        for (int e = 0; e < 4; ++e) {
            const float p = sr[r][e];
            const bf16_t hb = (bf16_t)p;
            phi[e] = hb; plo[e] = (bf16_t)(p - (float)hb);
            const float p2 = p * p;
            const bf16_t h2 = (bf16_t)p2;
            p2hi[e] = h2; p2lo[e] = (bf16_t)(p2 - (float)h2);
        }
        const int row = fw + r;
        *(bf16x4*)&Phi[row * 264 + lane * 4] = phi;
        *(bf16x4*)&Plo[row * 264 + lane * 4] = plo;
        *(bf16x4*)&P2h[row * 264 + lane * 4] = p2hi;
        *(bf16x4*)&P2l[row * 264 + lane * 4] = p2lo;
    }
    __syncthreads();

    // PV: B-fragment from transposed Vt — one 16B L2 load per MFMA pair
    const int tile = w & 3;
    const int isvar = w >> 2;
    const bf16_t* Pa = isvar ? P2h : Phi;
    const bf16_t* Pb = isvar ? P2l : Plo;
    const bf16_t* Vrow = (isvar ? Vtv : Vtm) + (size_t)h * 16384
                       + (size_t)(tile * 16 + fr) * 256 + fq * 8;
    f32x4 accp = {0.f, 0.f, 0.f, 0.f};
#pragma unroll
    for (int k0 = 0; k0 < 256; k0 += 32) {
        const int ka = k0 + fq * 8;
        bf16x8 a1 = *(const bf16x8*)&Pa[fr * 264 + ka];
        bf16x8 a2 = *(const bf16x8*)&Pb[fr * 264 + ka];
        bf16x8 bfr = *(const bf16x8*)(Vrow + k0);
        accp = __builtin_amdgcn_mfma_f32_16x16x32_bf16(a1, bfr, accp, 0, 0, 0);
        accp = __builtin_amdgcn_mfma_f32_16x16x32_bf16(a2, bfr, accp, 0, 0, 0);
    }

    bf16_t* Out = isvar ? Ovar : Omu;
#pragma unroll
    for (int reg = 0; reg < 4; ++reg) {
        const int qg = qt * 16 + fq * 4 + reg;
        const size_t ob = (size_t)qg * 1024 + h * 64 + tile * 16 + fr;
        Out[ob] = (bf16_t)accp[reg];
    }
}

// ============================================================================
// output projection: 256 blocks (32-row tiles), 1/CU, XCD co-sched (R6)
// ============================================================================
struct OutArgs {
    const bf16_t* A[2];
    const float*  W[2];
    const float*  bias[2];
    float*        dst[2];
    int           splus[2];
};

__global__ __launch_bounds__(256, 2) void out_gemm(OutArgs args) {
    __shared__ __align__(16) unsigned char smem[PROJ_SMEM];
    const int t = threadIdx.x;
    const int L = blockIdx.x;
    const int x = L & 7, o = L >> 3;
    const int g = (o >> 3) * 8 + x;
    const int m = o & 7;
    const int z = g >> 4;
    const int n_base = (g & 15) * 64;
    const int m_base = m * 32;

    const bf16_t* __restrict__ A    = args.A[z];
    const float*  __restrict__ W    = args.W[z];
    const float*  __restrict__ bias = args.bias[z];
    float*        __restrict__ dst  = args.dst[z];
    const int sp = args.splus[z];

    f32x4 ov[2];
    gemmT_core<false, 2>(A, W, m_base, n_base, smem, t, ov);

    const int cc = (t & 15) * 4;
    const f32x4 bv = *(const f32x4*)&bias[n_base + cc];
#pragma unroll
    for (int i = 0; i < 2; ++i) {
        const int row = (t >> 4) + i * 16;
        f32x4 v = ov[i] + bv;
        if (sp) {
            v[0] = softplus_f(v[0]); v[1] = softplus_f(v[1]);
            v[2] = softplus_f(v[2]); v[3] = softplus_f(v[3]);
        }
        *(f32x4*)&dst[(size_t)(m_base + row) * 1024 + n_base + cc] = v;
    }
}

// ---------------- launch ----------------
extern "C" void kernel_launch(void* const* d_in, const int* in_sizes, int n_in,
                              void* d_out, int out_size, void* d_ws, size_t ws_size,
                              hipStream_t stream) {
    const float* mu  = (const float*)d_in[0];
    const float* var = (const float*)d_in[1];
    uint8_t* ws = (uint8_t*)d_ws;

    float*  Proj = (float*)(ws);                               // 2 x 1 MB: Qm, Qv (f32)
    bf16_t* Vtm  = (bf16_t*)(ws + (2u << 20));                 // 512 KB [16][64][256]
    bf16_t* Vtv  = (bf16_t*)(ws + (2u << 20) + (512u << 10));  // 512 KB
    bf16_t* Obm  = (bf16_t*)(ws + (3u << 20));                 // 512 KB
    bf16_t* Obv  = (bf16_t*)(ws + (3u << 20) + (512u << 10));  // 512 KB
    bf16_t* Gbf  = (bf16_t*)(ws + (4u << 20));                 // 1 MB
    float*  cvec = (float*)(ws + (5u << 20));                  // 16 KB

    // 1) projections; V stored transposed bf16
    ProjArgs pr;
    pr.mu = mu; pr.var = var;
    for (int i = 0; i < 6; ++i) {
        pr.W[i]    = (const float*)d_in[2 + 2 * i];
        pr.bias[i] = (const float*)d_in[3 + 2 * i];
    }
    pr.Proj = Proj; pr.Vtm = Vtm; pr.Vtv = Vtv; pr.Gbf = Gbf; pr.cvec = cvec;
    proj_kernel<<<dim3(640), 256, 0, stream>>>(pr);

    // 2) attention (no V staging)
    attn_v8<<<dim3(256), 512, 0, stream>>>(Proj, Proj + 262144, Gbf, cvec,
                                           Vtm, Vtv, Obm, Obv);

    // 3) output projections
    OutArgs g3;
    g3.A[0] = Obm;  g3.W[0] = (const float*)d_in[14];
    g3.bias[0] = (const float*)d_in[15];
    g3.dst[0] = (float*)d_out;             g3.splus[0] = 0;
    g3.A[1] = Obv;  g3.W[1] = (const float*)d_in[16];
    g3.bias[1] = (const float*)d_in[17];
    g3.dst[1] = (float*)d_out + 262144;    g3.splus[1] = 1;
    out_gemm<<<dim3(256), 256, 0, stream>>>(g3);
}